// Round 6
// baseline (58.978 us; speedup 1.0000x reference)
//
#include <hip/hip_runtime.h>

#define BATCH 4
#define NPTS  8192
#define BN    (BATCH * NPTS)
#define QPT   8                    // queries per thread
#define CH    256                  // candidate chunk size (== blockDim)
#define NCH   (NPTS / CH)          // 32 chunks
#define QBLK  (NPTS / (256 * QPT)) // 4 query-blocks per batch

// order-preserving float <-> uint for unsigned atomicMin
__device__ __forceinline__ unsigned fkey(float f) {
    unsigned u = __float_as_uint(f);
    return u ^ (unsigned)(((int)u >> 31) | 0x80000000);
}
__device__ __forceinline__ float funkey(unsigned k) {
    unsigned u = k ^ ((k & 0x80000000u) ? 0x80000000u : 0xFFFFFFFFu);
    return __uint_as_float(u);
}

// ---- pack: (B*N,3) f32 -> (B*N) float4 {-2x, -2y, -2z, |p|^2} -------------
__global__ void pack_kernel(const float* __restrict__ preds,
                            const float* __restrict__ gts,
                            float4* __restrict__ packP,
                            float4* __restrict__ packG) {
    int i = blockIdx.x * blockDim.x + threadIdx.x;
    const float* src = (blockIdx.y == 0) ? preds : gts;
    float4* dst      = (blockIdx.y == 0) ? packP : packG;
    if (i < BN) {
        float x = src[3 * i], y = src[3 * i + 1], z = src[3 * i + 2];
        dst[i] = make_float4(-2.0f * x, -2.0f * y, -2.0f * z,
                             x * x + y * y + z * z);
    }
}

// ---- main: LDS-staged candidates, min over chunk, atomicMin(min+qsq) ------
// grid: (BATCH*QBLK, NCH, 2); block: 256
__global__ void __launch_bounds__(256, 4)
chamfer_min_kernel(const float4* __restrict__ packP,
                   const float4* __restrict__ packG,
                   unsigned* __restrict__ keys) {
    __shared__ float4 cl[CH];

    const int dir   = blockIdx.z;   // 0: queries=preds, cand=gts ; 1: swapped
    const int chunk = blockIdx.y;
    const int b     = blockIdx.x / QBLK;
    const int qb    = blockIdx.x % QBLK;
    const int t     = threadIdx.x;

    const float4* __restrict__ qp = (dir == 0) ? packP : packG;
    const float4* __restrict__ cp = (dir == 0) ? packG : packP;

    // stage candidate chunk into LDS (one coalesced float4 per thread)
    cl[t] = cp[b * NPTS + chunk * CH + t];

    const int qbase = b * NPTS + qb * (256 * QPT) + t;

    float qx[QPT], qy[QPT], qz[QPT], qsq[QPT], m[QPT];
#pragma unroll
    for (int k = 0; k < QPT; ++k) {
        float4 v = qp[qbase + k * 256];       // scaled array; recover raw q
        qx[k]  = -0.5f * v.x;
        qy[k]  = -0.5f * v.y;
        qz[k]  = -0.5f * v.z;
        qsq[k] = v.w;
        m[k] = 1e30f;
    }

    __syncthreads();

#pragma unroll 2
    for (int c = 0; c < CH; c += 2) {
        float4 c0 = cl[c];        // uniform address -> LDS broadcast
        float4 c1 = cl[c + 1];
#pragma unroll
        for (int k = 0; k < QPT; ++k) {
            float d0 = fmaf(qx[k], c0.x, fmaf(qy[k], c0.y, fmaf(qz[k], c0.z, c0.w)));
            float d1 = fmaf(qx[k], c1.x, fmaf(qy[k], c1.y, fmaf(qz[k], c1.z, c1.w)));
            m[k] = fminf(m[k], fminf(d0, d1));   // -> v_min3_f32
        }
    }

    unsigned* __restrict__ kout = keys + (size_t)dir * BN;
#pragma unroll
    for (int k = 0; k < QPT; ++k)
        atomicMin(&kout[qbase + k * 256], fkey(m[k] + qsq[k]));
}

// ---- finalize: decode key, global sum -------------------------------------
// grid: 2*B*N/256 = 256 blocks
__global__ void __launch_bounds__(256)
finalize_kernel(const unsigned* __restrict__ keys, float* __restrict__ out) {
    __shared__ float red[4];
    const int idx = blockIdx.x * 256 + threadIdx.x;   // [0, 2*B*N)

    float val = funkey(keys[idx]);

#pragma unroll
    for (int off = 32; off > 0; off >>= 1)
        val += __shfl_down(val, off, 64);

    const int wave = threadIdx.x >> 6;
    const int lane = threadIdx.x & 63;
    if (lane == 0) red[wave] = val;
    __syncthreads();
    if (threadIdx.x == 0)
        atomicAdd(out, red[0] + red[1] + red[2] + red[3]);
}

extern "C" void kernel_launch(void* const* d_in, const int* in_sizes, int n_in,
                              void* d_out, int out_size, void* d_ws, size_t ws_size,
                              hipStream_t stream) {
    const float* preds = (const float*)d_in[0];
    const float* gts   = (const float*)d_in[1];
    float* out = (float*)d_out;

    // workspace layout: packs 1 MB, keys 256 KB
    char* ws = (char*)d_ws;
    float4*   packP = (float4*)ws;                                // 512 KB
    float4*   packG = (float4*)(ws + (size_t)BN * 16);            // 512 KB
    unsigned* keys  = (unsigned*)(ws + (size_t)2 * BN * 16);      // 256 KB

    dim3 gpack((BN + 255) / 256, 2);
    pack_kernel<<<gpack, 256, 0, stream>>>(preds, gts, packP, packG);

    hipMemsetAsync(keys, 0xFF, (size_t)2 * BN * sizeof(unsigned), stream);
    hipMemsetAsync(out, 0, sizeof(float), stream);

    dim3 gmain(BATCH * QBLK, NCH, 2);
    chamfer_min_kernel<<<gmain, 256, 0, stream>>>(packP, packG, keys);

    finalize_kernel<<<2 * BN / 256, 256, 0, stream>>>(keys, out);
}

// Round 7
// 44.746 us; speedup vs baseline: 1.3181x; 1.3181x over previous
//
#include <hip/hip_runtime.h>

#define BATCH 4
#define NPTS  8192
#define BN    (BATCH * NPTS)   // 32768

typedef _Float16 f16;
typedef f16   f16x8  __attribute__((ext_vector_type(8)));
typedef float f32x16 __attribute__((ext_vector_type(16)));

// order-preserving float <-> uint for unsigned atomicMin
__device__ __forceinline__ unsigned fkey(float f) {
    unsigned u = __float_as_uint(f);
    return u ^ (unsigned)(((int)u >> 31) | 0x80000000);
}
__device__ __forceinline__ float funkey(unsigned k) {
    unsigned u = k ^ ((k & 0x80000000u) ? 0x80000000u : 0xFFFFFFFFu);
    return __uint_as_float(u);
}

// ---- pack: point -> f16x8 {-2x, -2y, -2z, csq_hi, csq_lo, 0, 0, 0} --------
// coords quantized to f16; csq computed in f32 FROM the quantized coords and
// split hi/lo so the MFMA reconstructs csq to ~2^-22. -2*xh is exact in f16.
__global__ void pack_kernel(const float* __restrict__ preds,
                            const float* __restrict__ gts,
                            f16x8* __restrict__ cP,
                            f16x8* __restrict__ cG) {
    int i = blockIdx.x * 256 + threadIdx.x;
    const float* src = blockIdx.y ? gts : preds;
    f16x8* dst       = blockIdx.y ? cG : cP;
    if (i < BN) {
        float x = src[3 * i], y = src[3 * i + 1], z = src[3 * i + 2];
        f16 xh = (f16)x, yh = (f16)y, zh = (f16)z;
        float xf = (float)xh, yf = (float)yh, zf = (float)zh;
        float csq = xf * xf + yf * yf + zf * zf;
        f16 ch = (f16)csq;
        f16 cl = (f16)(csq - (float)ch);
        f16x8 v;
        v[0] = xh * (f16)(-2.0f);
        v[1] = yh * (f16)(-2.0f);
        v[2] = zh * (f16)(-2.0f);
        v[3] = ch;
        v[4] = cl;
        v[5] = (f16)0.0f; v[6] = (f16)0.0f; v[7] = (f16)0.0f;
        dst[i] = v;
    }
}

// ---- main: MFMA pairwise distances, per-wave min, atomicMin merge ---------
// grid: 1024 blocks x 256. Each wave: 64 queries (2 A-frags) x 2048 candidates.
// blockIdx: bd(3b: b,dir) | qt4(5b) | s(2b); wave-in-block selects qt sub-tile.
// v_mfma_f32_32x32x16_f16: A 32x16 (lane: row=l&31, k=8*(l>>5)+j),
// B 16x32 (lane: col=l&31, k=8*(l>>5)+j), D: col=l&31, row=(r&3)+8*(r>>2)+4*(l>>5).
__global__ void __launch_bounds__(256, 4)
chamfer_mfma_kernel(const f16x8* __restrict__ cP,
                    const f16x8* __restrict__ cG,
                    const f16x8* __restrict__ zp,
                    unsigned* __restrict__ keys) {
    const int lane   = threadIdx.x & 63;
    const int wavein = threadIdx.x >> 6;

    const int bd  = blockIdx.x >> 7;            // 0..7 : b*2 + dir
    const int rem = blockIdx.x & 127;
    const int s   = rem & 3;                     // candidate split 0..3
    const int qt  = (rem >> 2) * 4 + wavein;     // query tile 0..127
    const int b   = bd >> 1;
    const int dir = bd & 1;                      // 0: q=preds,c=gts ; 1: swapped

    const f16x8* __restrict__ Q = dir ? cG : cP;
    const f16x8* __restrict__ C = dir ? cP : cG;

    const bool act = lane < 32;
    const int  l31 = lane & 31;

    // ---- A fragments: two 32-query tiles, transformed from candidate-form
    const int q0 = b * NPTS + qt * 64;
    const f16x8* pA0 = act ? (Q + q0 + l31)      : zp;
    const f16x8* pA1 = act ? (Q + q0 + 32 + l31) : zp;
    f16x8 a0r = *pA0;
    f16x8 a1r = *pA1;
    const f16 nh  = (f16)(-0.5f);                // -0.5 * (-2x) = x, exact
    const f16 one = act ? (f16)1.0f : (f16)0.0f;
    f16x8 a0, a1;
    a0[0] = a0r[0] * nh; a0[1] = a0r[1] * nh; a0[2] = a0r[2] * nh;
    a0[3] = one; a0[4] = one; a0[5] = (f16)0.0f; a0[6] = (f16)0.0f; a0[7] = (f16)0.0f;
    a1[0] = a1r[0] * nh; a1[1] = a1r[1] * nh; a1[2] = a1r[2] * nh;
    a1[3] = one; a1[4] = one; a1[5] = (f16)0.0f; a1[6] = (f16)0.0f; a1[7] = (f16)0.0f;

    // ---- candidate stream pointers (lanes >=32 pinned to zero page)
    const int c0 = b * NPTS + s * 2048;
    const f16x8* pB0 = act ? (C + c0 + l31)      : zp;
    const f16x8* pB1 = act ? (C + c0 + 32 + l31) : zp;
    const long step = act ? 64 : 0;              // in f16x8 elements

    f32x16 m0, m1, zacc;
#pragma unroll
    for (int i = 0; i < 16; ++i) { m0[i] = 1e30f; m1[i] = 1e30f; zacc[i] = 0.0f; }

    for (int it = 0; it < 32; ++it) {            // 32 iters x 64 candidates
        f16x8 b0 = *pB0;
        f16x8 b1 = *pB1;
        pB0 += step; pB1 += step;
        // D = csq - 2<q,c> (csq folded in via K-slots 3,4)
        f32x16 d00 = __builtin_amdgcn_mfma_f32_32x32x16_f16(a0, b0, zacc, 0, 0, 0);
        f32x16 d01 = __builtin_amdgcn_mfma_f32_32x32x16_f16(a0, b1, zacc, 0, 0, 0);
#pragma unroll
        for (int i = 0; i < 16; ++i)
            m0[i] = fminf(m0[i], fminf(d00[i], d01[i]));   // -> v_min3_f32
        f32x16 d10 = __builtin_amdgcn_mfma_f32_32x32x16_f16(a1, b0, zacc, 0, 0, 0);
        f32x16 d11 = __builtin_amdgcn_mfma_f32_32x32x16_f16(a1, b1, zacc, 0, 0, 0);
#pragma unroll
        for (int i = 0; i < 16; ++i)
            m1[i] = fminf(m1[i], fminf(d10[i], d11[i]));
    }

    // ---- cross-lane min over the 32 columns (candidates) of each row
#pragma unroll
    for (int i = 0; i < 16; ++i) {
        float v0 = m0[i], v1 = m1[i];
#pragma unroll
        for (int mask = 1; mask <= 16; mask <<= 1) {
            v0 = fminf(v0, __shfl_xor(v0, mask, 64));
            v1 = fminf(v1, __shfl_xor(v1, mask, 64));
        }
        m0[i] = v0; m1[i] = v1;
    }

    // ---- merge: lanes 0 and 32 own row-halves (row = (r&3)+8*(r>>2)+4*(lane>>5))
    if ((lane & 31) == 0) {
        unsigned* __restrict__ kout = keys + (size_t)dir * BN;
        const int rbase = q0 + ((lane >> 5) << 2);
#pragma unroll
        for (int r = 0; r < 16; ++r) {
            const int row = (r & 3) + 8 * (r >> 2);
            atomicMin(&kout[rbase + row],      fkey(m0[r]));
            atomicMin(&kout[rbase + 32 + row], fkey(m1[r]));
        }
    }
}

// ---- finalize: decode key, + qsq (from quantized pack), global sum --------
// grid: 2*BN/256 = 256 blocks
__global__ void __launch_bounds__(256)
finalize_kernel(const unsigned* __restrict__ keys,
                const f16x8* __restrict__ cP,
                const f16x8* __restrict__ cG,
                float* __restrict__ out) {
    __shared__ float red[4];
    const int idx = blockIdx.x * 256 + threadIdx.x;   // [0, 2*BN)
    const int dir = idx >> 15;
    const int q   = idx & (BN - 1);

    f16x8 v = (dir ? cG : cP)[q];                 // query's own pack
    const float qsq = (float)v[3] + (float)v[4];  // csq_hi + csq_lo
    float val = funkey(keys[idx]) + qsq;

#pragma unroll
    for (int off = 32; off > 0; off >>= 1)
        val += __shfl_down(val, off, 64);

    const int wave = threadIdx.x >> 6;
    const int lane = threadIdx.x & 63;
    if (lane == 0) red[wave] = val;
    __syncthreads();
    if (threadIdx.x == 0)
        atomicAdd(out, red[0] + red[1] + red[2] + red[3]);
}

extern "C" void kernel_launch(void* const* d_in, const int* in_sizes, int n_in,
                              void* d_out, int out_size, void* d_ws, size_t ws_size,
                              hipStream_t stream) {
    const float* preds = (const float*)d_in[0];
    const float* gts   = (const float*)d_in[1];
    float* out = (float*)d_out;

    // ws layout: zeropage 256B | keys 256KB | cPackP 512KB | cPackG 512KB
    char* ws = (char*)d_ws;
    f16x8*    zp   = (f16x8*)ws;
    unsigned* keys = (unsigned*)(ws + 256);
    f16x8*    cP   = (f16x8*)(ws + 256 + (size_t)2 * BN * 4);
    f16x8*    cG   = cP + BN;

    hipMemsetAsync(ws, 0, 256, stream);                               // zero page
    hipMemsetAsync(keys, 0xFF, (size_t)2 * BN * sizeof(unsigned), stream);
    hipMemsetAsync(out, 0, sizeof(float), stream);

    dim3 gpack(BN / 256, 2);
    pack_kernel<<<gpack, 256, 0, stream>>>(preds, gts, cP, cG);

    chamfer_mfma_kernel<<<1024, 256, 0, stream>>>(cP, cG, zp, keys);

    finalize_kernel<<<2 * BN / 256, 256, 0, stream>>>(keys, cP, cG, out);
}

// Round 8
// 39.175 us; speedup vs baseline: 1.5055x; 1.1422x over previous
//
#include <hip/hip_runtime.h>

#define BATCH 4
#define NPTS  8192
#define BN    (BATCH * NPTS)   // 32768

typedef _Float16 f16;
typedef f16   f16x8  __attribute__((ext_vector_type(8)));
typedef float f32x16 __attribute__((ext_vector_type(16)));

// order-preserving float <-> uint for unsigned atomicMin
__device__ __forceinline__ unsigned fkey(float f) {
    unsigned u = __float_as_uint(f);
    return u ^ (unsigned)(((int)u >> 31) | 0x80000000);
}
__device__ __forceinline__ float funkey(unsigned k) {
    unsigned u = k ^ ((k & 0x80000000u) ? 0x80000000u : 0xFFFFFFFFu);
    return __uint_as_float(u);
}

// ---- pack+init: point -> f16x8 {-2x,-2y,-2z, csq_hi, csq_lo, 0,0,0} -------
// Also initializes keys (one word per thread), the zero page, and out.
// grid: (BN/256, 2) x 256
__global__ void pack_kernel(const float* __restrict__ preds,
                            const float* __restrict__ gts,
                            f16x8* __restrict__ cP,
                            f16x8* __restrict__ cG,
                            unsigned* __restrict__ keys,
                            f16x8* __restrict__ zp,
                            float* __restrict__ out) {
    const int i     = blockIdx.x * 256 + threadIdx.x;
    const int which = blockIdx.y;

    keys[(size_t)which * BN + i] = 0xFFFFFFFFu;   // +inf key

    if (which == 0 && i == 0) {
        *out = 0.0f;
        f16x8 z;
#pragma unroll
        for (int j = 0; j < 8; ++j) z[j] = (f16)0.0f;
        zp[0] = z; zp[1] = z;
    }

    const float* src = which ? gts : preds;
    f16x8* dst       = which ? cG : cP;
    float x = src[3 * i], y = src[3 * i + 1], z = src[3 * i + 2];
    f16 xh = (f16)x, yh = (f16)y, zh = (f16)z;
    float xf = (float)xh, yf = (float)yh, zf = (float)zh;
    float csq = xf * xf + yf * yf + zf * zf;
    f16 ch = (f16)csq;
    f16 cl = (f16)(csq - (float)ch);
    f16x8 v;
    v[0] = xh * (f16)(-2.0f);
    v[1] = yh * (f16)(-2.0f);
    v[2] = zh * (f16)(-2.0f);
    v[3] = ch;
    v[4] = cl;
    v[5] = (f16)0.0f; v[6] = (f16)0.0f; v[7] = (f16)0.0f;
    dst[i] = v;
}

// ---- main: MFMA pairwise distances, per-wave min, atomicMin merge ---------
// grid: 1024 blocks x 256. Each wave: 64 queries (2 A-frags) x 2048 candidates.
// v_mfma_f32_32x32x16_f16: A 32x16 (lane: row=l&31, k=8*(l>>5)+j),
// B 16x32 (lane: col=l&31, k=8*(l>>5)+j), D: col=l&31, row=(r&3)+8*(r>>2)+4*(l>>5).
__global__ void __launch_bounds__(256, 4)
chamfer_mfma_kernel(const f16x8* __restrict__ cP,
                    const f16x8* __restrict__ cG,
                    const f16x8* __restrict__ zp,
                    unsigned* __restrict__ keys) {
    const int lane   = threadIdx.x & 63;
    const int wavein = threadIdx.x >> 6;

    const int bd  = blockIdx.x >> 7;            // 0..7 : b*2 + dir
    const int rem = blockIdx.x & 127;
    const int s   = rem & 3;                     // candidate split 0..3
    const int qt  = (rem >> 2) * 4 + wavein;     // query tile 0..127
    const int b   = bd >> 1;
    const int dir = bd & 1;                      // 0: q=preds,c=gts ; 1: swapped

    const f16x8* __restrict__ Q = dir ? cG : cP;
    const f16x8* __restrict__ C = dir ? cP : cG;

    const bool act = lane < 32;
    const int  l31 = lane & 31;

    // ---- A fragments: two 32-query tiles, transformed from candidate-form
    const int q0 = b * NPTS + qt * 64;
    const f16x8* pA0 = act ? (Q + q0 + l31)      : zp;
    const f16x8* pA1 = act ? (Q + q0 + 32 + l31) : zp;
    f16x8 a0r = *pA0;
    f16x8 a1r = *pA1;
    const f16 nh  = (f16)(-0.5f);                // -0.5 * (-2x) = x, exact
    const f16 one = act ? (f16)1.0f : (f16)0.0f;
    f16x8 a0, a1;
    a0[0] = a0r[0] * nh; a0[1] = a0r[1] * nh; a0[2] = a0r[2] * nh;
    a0[3] = one; a0[4] = one; a0[5] = (f16)0.0f; a0[6] = (f16)0.0f; a0[7] = (f16)0.0f;
    a1[0] = a1r[0] * nh; a1[1] = a1r[1] * nh; a1[2] = a1r[2] * nh;
    a1[3] = one; a1[4] = one; a1[5] = (f16)0.0f; a1[6] = (f16)0.0f; a1[7] = (f16)0.0f;

    // ---- candidate stream pointers (lanes >=32 pinned to zero page)
    const int c0 = b * NPTS + s * 2048;
    const f16x8* pB0 = act ? (C + c0 + l31)      : zp;
    const f16x8* pB1 = act ? (C + c0 + 32 + l31) : zp;
    const long step = act ? 64 : 0;              // in f16x8 elements

    f32x16 m0, m1, zacc;
#pragma unroll
    for (int i = 0; i < 16; ++i) { m0[i] = 1e30f; m1[i] = 1e30f; zacc[i] = 0.0f; }

    for (int it = 0; it < 32; ++it) {            // 32 iters x 64 candidates
        f16x8 b0 = *pB0;
        f16x8 b1 = *pB1;
        pB0 += step; pB1 += step;
        // D = csq - 2<q,c> (csq folded in via K-slots 3,4)
        f32x16 d00 = __builtin_amdgcn_mfma_f32_32x32x16_f16(a0, b0, zacc, 0, 0, 0);
        f32x16 d01 = __builtin_amdgcn_mfma_f32_32x32x16_f16(a0, b1, zacc, 0, 0, 0);
#pragma unroll
        for (int i = 0; i < 16; ++i)
            m0[i] = fminf(m0[i], fminf(d00[i], d01[i]));   // -> v_min3_f32
        f32x16 d10 = __builtin_amdgcn_mfma_f32_32x32x16_f16(a1, b0, zacc, 0, 0, 0);
        f32x16 d11 = __builtin_amdgcn_mfma_f32_32x32x16_f16(a1, b1, zacc, 0, 0, 0);
#pragma unroll
        for (int i = 0; i < 16; ++i)
            m1[i] = fminf(m1[i], fminf(d10[i], d11[i]));
    }

    // ---- cross-lane min over the 32 columns (candidates) of each row
#pragma unroll
    for (int i = 0; i < 16; ++i) {
        float v0 = m0[i], v1 = m1[i];
#pragma unroll
        for (int mask = 1; mask <= 16; mask <<= 1) {
            v0 = fminf(v0, __shfl_xor(v0, mask, 64));
            v1 = fminf(v1, __shfl_xor(v1, mask, 64));
        }
        m0[i] = v0; m1[i] = v1;
    }

    // ---- merge: lanes 0 and 32 own row-halves (row = (r&3)+8*(r>>2)+4*(lane>>5))
    if ((lane & 31) == 0) {
        unsigned* __restrict__ kout = keys + (size_t)dir * BN;
        const int rbase = q0 + ((lane >> 5) << 2);
#pragma unroll
        for (int r = 0; r < 16; ++r) {
            const int row = (r & 3) + 8 * (r >> 2);
            atomicMin(&kout[rbase + row],      fkey(m0[r]));
            atomicMin(&kout[rbase + 32 + row], fkey(m1[r]));
        }
    }
}

// ---- finalize: decode key, + qsq (from quantized pack), global sum --------
// grid: 2*BN/256 = 256 blocks
__global__ void __launch_bounds__(256)
finalize_kernel(const unsigned* __restrict__ keys,
                const f16x8* __restrict__ cP,
                const f16x8* __restrict__ cG,
                float* __restrict__ out) {
    __shared__ float red[4];
    const int idx = blockIdx.x * 256 + threadIdx.x;   // [0, 2*BN)
    const int dir = idx >> 15;
    const int q   = idx & (BN - 1);

    f16x8 v = (dir ? cG : cP)[q];                 // query's own pack
    const float qsq = (float)v[3] + (float)v[4];  // csq_hi + csq_lo
    float val = funkey(keys[idx]) + qsq;

#pragma unroll
    for (int off = 32; off > 0; off >>= 1)
        val += __shfl_down(val, off, 64);

    const int wave = threadIdx.x >> 6;
    const int lane = threadIdx.x & 63;
    if (lane == 0) red[wave] = val;
    __syncthreads();
    if (threadIdx.x == 0)
        atomicAdd(out, red[0] + red[1] + red[2] + red[3]);
}

extern "C" void kernel_launch(void* const* d_in, const int* in_sizes, int n_in,
                              void* d_out, int out_size, void* d_ws, size_t ws_size,
                              hipStream_t stream) {
    const float* preds = (const float*)d_in[0];
    const float* gts   = (const float*)d_in[1];
    float* out = (float*)d_out;

    // ws layout: zeropage 256B | keys 256KB | cPackP 512KB | cPackG 512KB
    char* ws = (char*)d_ws;
    f16x8*    zp   = (f16x8*)ws;
    unsigned* keys = (unsigned*)(ws + 256);
    f16x8*    cP   = (f16x8*)(ws + 256 + (size_t)2 * BN * 4);
    f16x8*    cG   = cP + BN;

    dim3 gpack(BN / 256, 2);
    pack_kernel<<<gpack, 256, 0, stream>>>(preds, gts, cP, cG, keys, zp, out);

    chamfer_mfma_kernel<<<1024, 256, 0, stream>>>(cP, cG, zp, keys);

    finalize_kernel<<<2 * BN / 256, 256, 0, stream>>>(keys, cP, cG, out);
}